// Round 12
// baseline (141.791 us; speedup 1.0000x reference)
//
#include <hip/hip_runtime.h>

// LIF neuron forward, v7: amortize fixed per-phase latency (CHUNK 64->256).
// V = leak*V + I; spike = (V >= 1); V -= spike.
// current: [B=8, S=4096, D=1024] f32, membrane: [B, D] f32.
// Outputs concatenated: spikes [B,S,D] then mem_final [B,D], all f32.
//
// Evidence: v5 (128blk,CPB64) and v6 (256blk,CPB32) both pin at
// ~3600-3750 cyc/phase regardless of per-phase traffic -> fixed per-phase
// overhead F ~2000-2500 cyc (barrier skew + first-LDS-read latency +
// drains), paid NH times. v7: CHUNK=256, NH=16 -> F paid 16x not 64x.
// LDS 128KB: in_ring[2][256][32] + out_ring[2][256][32]. Phases (~6000cy)
// dwarf HBM latency so the producer runs distance-1 with a plain vmcnt(0)
// drain, off the critical path.
//
// Numerics (validated r5-r11, absmax 7.6e-6): forward spike == hard
// threshold exactly in fp32; fp contract(off) pins mul-then-add rounding.

#define LIF_B 8
#define LIF_S 4096
#define LIF_D 1024
#define CHUNK 256
#define NH    (LIF_S / CHUNK)   // 16
#define CPB   32                // channels per block

typedef __attribute__((address_space(3))) unsigned int lds_uint;
typedef const __attribute__((address_space(1))) unsigned int glb_uint;

// stage one 32KB chunk (256 rows x 32 ch) with 32 x 1KB global_load_lds.
// lane L -> row (L>>3) within an 8-row group, float col (L&7)*4.
// LDS dest is wave-uniform base (linear); per-lane addressing on global src.
__device__ __forceinline__ void stage_chunk256(const float* gwin, int tb,
                                               int prow, int pcol,
                                               float* slotbase) {
    #pragma unroll
    for (int f = 0; f < CHUNK / 8; ++f) {   // 32 groups of 8 rows
        const float* src = gwin + (size_t)(tb + 8 * f + prow) * LIF_D + pcol;
        __builtin_amdgcn_global_load_lds(
            (glb_uint*)(const void*)src,
            (lds_uint*)(void*)(slotbase + (size_t)f * 256), 16, 0, 0);
    }
}

__global__ __launch_bounds__(256, 1) void lif_v7_kernel(
    const float* __restrict__ current,
    const float* __restrict__ membrane,
    float* __restrict__ spikes,
    float* __restrict__ mem_out)
{
    #pragma clang fp contract(off)

    __shared__ __align__(16) float in_ring [2][CHUNK][CPB];   // 64 KB
    __shared__ __align__(16) float out_ring[2][CHUNK][CPB];   // 64 KB

    const int wid  = threadIdx.x >> 6;   // 0=consumer 1=producer 2,3=writers
    const int lane = threadIdx.x & 63;
    const int blk  = blockIdx.x;         // 0..255
    const int bb   = blk >> 5;           // batch (1024/32 = 32 ch-blocks)
    const int ch0  = (blk & 31) * CPB;

    const float* gwin  = current + (size_t)bb * LIF_S * LIF_D + ch0;
    float*       sbase = spikes  + (size_t)bb * LIF_S * LIF_D + ch0;

    const int prow = lane >> 3;          // 0..7 : row within 8-row group
    const int pcol = (lane & 7) * 4;     // float col (16B units)

    float mem = 0.0f;

    // ---- prologue: producer stages chunk 0; consumer loads membrane ----
    if (wid == 1) {
        stage_chunk256(gwin, 0, prow, pcol, &in_ring[0][0][0]);
        asm volatile("s_waitcnt vmcnt(0)" ::: "memory");
    } else if (wid == 0 && lane < CPB) {
        mem = membrane[bb * LIF_D + ch0 + lane];
    }
    __builtin_amdgcn_s_barrier();
    asm volatile("" ::: "memory");

    for (int h = 0; h < NH; ++h) {
        if (wid == 0) {
            if (lane < CPB) {
                // ---- consumer: chunk h, immediate-offset LDS addressing ----
                const float* ib = &in_ring [h & 1][0][lane];
                float*       ob = &out_ring[h & 1][0][lane];

                float pre[8], nxt[8];
                #pragma unroll
                for (int j = 0; j < 8; ++j) pre[j] = ib[j * CPB];

                for (int r0 = 0; r0 < CHUNK; r0 += 8) {
                    if (r0 + 8 < CHUNK) {
                        #pragma unroll
                        for (int j = 0; j < 8; ++j) nxt[j] = ib[(r0 + 8 + j) * CPB];
                    }
                    #pragma unroll
                    for (int j = 0; j < 8; ++j) {
                        const float v = 0.9f * mem + pre[j];   // mul-then-add
                        const float w = v - 1.0f;              // off chain
                        const bool  f = (v >= 1.0f);
                        ob[(r0 + j) * CPB] = f ? 1.0f : 0.0f;
                        mem = f ? w : v;                       // soft reset
                    }
                    #pragma unroll
                    for (int j = 0; j < 8; ++j) pre[j] = nxt[j];
                }
            }
            asm volatile("s_waitcnt lgkmcnt(0)" ::: "memory");
        } else if (wid == 1) {
            // ---- producer: stage chunk h+1 into the slot consumer just left
            if (h + 1 < NH) {
                stage_chunk256(gwin, (h + 1) * CHUNK, prow, pcol,
                               &in_ring[(h + 1) & 1][0][0]);
                asm volatile("s_waitcnt vmcnt(0)" ::: "memory");
            }
        } else {
            // ---- writers: flush out[h-1] (16 x 1KB each) ----
            if (h >= 1) {
                const int tbase = (h - 1) * CHUNK;
                const float4* o4 = (const float4*)&out_ring[(h - 1) & 1][0][0];
                #pragma unroll
                for (int k = 0; k < CHUNK / 16; ++k) {        // 16 per wave
                    const int f = (wid - 2) + 2 * k;          // 32 groups
                    const float4 vv = o4[f * 64 + lane];      // 8 rows x 8 f4
                    const int    t  = tbase + 8 * f + prow;
                    *(float4*)(sbase + (size_t)t * LIF_D + pcol) = vv;
                }
                asm volatile("s_waitcnt lgkmcnt(0)" ::: "memory");
            }
        }
        __builtin_amdgcn_s_barrier();
        asm volatile("" ::: "memory");
    }

    // ---- epilogue: flush out[NH-1]; store final membrane ----
    if (wid >= 2) {
        const int tbase = (NH - 1) * CHUNK;
        const float4* o4 = (const float4*)&out_ring[(NH - 1) & 1][0][0];
        #pragma unroll
        for (int k = 0; k < CHUNK / 16; ++k) {
            const int f = (wid - 2) + 2 * k;
            const float4 vv = o4[f * 64 + lane];
            const int    t  = tbase + 8 * f + prow;
            *(float4*)(sbase + (size_t)t * LIF_D + pcol) = vv;
        }
    } else if (wid == 0 && lane < CPB) {
        mem_out[bb * LIF_D + ch0 + lane] = mem;
    }
}

extern "C" void kernel_launch(void* const* d_in, const int* in_sizes, int n_in,
                              void* d_out, int out_size, void* d_ws, size_t ws_size,
                              hipStream_t stream) {
    const float* current  = (const float*)d_in[0];   // [8, 4096, 1024]
    const float* membrane = (const float*)d_in[1];   // [8, 1024]

    float* spikes  = (float*)d_out;                                 // [8,4096,1024]
    float* mem_out = (float*)d_out + (size_t)LIF_B * LIF_S * LIF_D; // [8,1024]

    dim3 block(256);                    // w0 consumer, w1 producer, w2-3 writers
    dim3 grid(LIF_B * LIF_D / CPB);     // 256 blocks (32 channels each)

    hipLaunchKernelGGL(lif_v7_kernel, grid, block, 0, stream,
                       current, membrane, spikes, mem_out);
}

// Round 13
// 128.711 us; speedup vs baseline: 1.1016x; 1.1016x over previous
//
#include <hip/hip_runtime.h>

// LIF neuron forward, v8: direct-global consumer with hand-counted vmcnt
// pipeline + L2 primer wave + writer offload.
// V = leak*V + I; spike = (V >= 1); V -= spike.
// current: [B=8, S=4096, D=1024] f32, membrane: [B, D] f32.
// Outputs concatenated: spikes [B,S,D] then mem_final [B,D], all f32.
//
// Evidence r5-r12: per-step cost ~55cy invariant to producer/writer/barrier/
// grid changes -> consumer-internal. Model: lgkm read/write coupling bubbles
// (~15cy/step) from interleaved ds_read prefetch + ds_write spikes sharing
// one counter. v8 removes consumer LDS READS: 16-deep register pipeline of
// inline-asm global_load_dword with per-step s_waitcnt vmcnt(15) tied to
// the consumed value ("+v" -> unhoistable). Input pipeline is barrier-free
// and runs continuously across phases. w1 primes rows into L2 via
// global_load_lds->dummy sink (correctness-independent). Spikes ds_write ->
// out_ring -> w2/w3 flush b128 (v5-proven protocol).
//
// Numerics (validated r5-r12, absmax 7.6e-6): forward spike == hard
// threshold exactly in fp32; fp contract(off) pins mul-then-add rounding.

#define LIF_B 8
#define LIF_S 4096
#define LIF_D 1024
#define CHUNK 64
#define NH    (LIF_S / CHUNK)   // 64
#define CPB   64                // channels per block

typedef __attribute__((address_space(3))) unsigned int lds_uint;
typedef const __attribute__((address_space(1))) unsigned int glb_uint;

// prime one 16KB chunk (64 rows x 64 ch) into L2: 16 x 1KB global_load_lds
// into a dummy LDS sink (data is never read from LDS; this only warms L2).
__device__ __forceinline__ void prime_chunk(const float* gwin, int tb,
                                            int prow, int pcol, float* sink) {
    #pragma unroll
    for (int f = 0; f < CHUNK / 4; ++f) {
        const float* src = gwin + (size_t)(tb + 4 * f + prow) * LIF_D + pcol;
        __builtin_amdgcn_global_load_lds(
            (glb_uint*)(const void*)src,
            (lds_uint*)(void*)sink, 16, 0, 0);
    }
}

__global__ __launch_bounds__(256, 1) void lif_v8_kernel(
    const float* __restrict__ current,
    const float* __restrict__ membrane,
    float* __restrict__ spikes,
    float* __restrict__ mem_out)
{
    #pragma clang fp contract(off)

    __shared__ __align__(16) float out_ring[2][CHUNK][CPB];  // 32 KB
    __shared__ __align__(16) float dummy[256];               // 1 KB primer sink

    const int wid  = threadIdx.x >> 6;   // 0=consumer 1=primer 2,3=writers
    const int lane = threadIdx.x & 63;
    const int blk  = blockIdx.x;         // 0..127
    const int bb   = blk >> 4;           // batch
    const int ch0  = (blk & 15) * CPB;

    const float* gwin  = current + (size_t)bb * LIF_S * LIF_D + ch0;
    float*       sbase = spikes  + (size_t)bb * LIF_S * LIF_D + ch0;

    const int prow = lane >> 4;          // primer/writer 4-row mapping
    const int pcol = (lane & 15) * 4;

    float mem = 0.0f;
    float buf[16];                       // rotating load pipeline (static idx)
    unsigned voff = (unsigned)lane * 4u; // byte offset of (t=0, my channel)
    const unsigned long long gb = (unsigned long long)(uintptr_t)gwin;

    // ---- prologue ----
    if (wid == 0) {
        mem = membrane[bb * LIF_D + ch0 + lane];
        // fill the 16-deep pipeline (t = 0..15)
        #pragma unroll
        for (int k = 0; k < 16; ++k) {
            asm volatile("global_load_dword %0, %1, %2"
                         : "=v"(buf[k]) : "v"(voff), "s"(gb));
            voff += LIF_D * 4u;
        }
    } else if (wid == 1) {
        prime_chunk(gwin, 0 * CHUNK, prow, pcol, dummy);
        prime_chunk(gwin, 1 * CHUNK, prow, pcol, dummy);
        asm volatile("s_waitcnt vmcnt(0)" ::: "memory");
    }
    __builtin_amdgcn_s_barrier();
    asm volatile("" ::: "memory");

    for (int h = 0; h < NH; ++h) {
        if (wid == 0) {
            // ---- consumer: 64 steps; input via counted-vmcnt reg pipeline ----
            float* ob = &out_ring[h & 1][0][lane];
            const bool pf = (h < NH - 1);
            #pragma unroll
            for (int j = 0; j < CHUNK; ++j) {
                // wait until load j landed (<=15 newer loads outstanding);
                // tying the value makes the wait unhoistable past the use.
                asm volatile("s_waitcnt vmcnt(15)" : "+v"(buf[j & 15]));
                const float c = buf[j & 15];
                const float v = 0.9f * mem + c;    // mul-then-add (no FMA)
                const float w = v - 1.0f;          // off critical path
                const bool  f = (v >= 1.0f);
                ob[j * CPB] = f ? 1.0f : 0.0f;     // spike -> LDS (write-only)
                mem = f ? w : v;                   // soft reset
                if (pf || j < CHUNK - 16) {        // issue load t+16
                    asm volatile("global_load_dword %0, %1, %2"
                                 : "=v"(buf[j & 15]) : "v"(voff), "s"(gb));
                    voff += LIF_D * 4u;
                }
            }
            asm volatile("s_waitcnt lgkmcnt(0)" ::: "memory");
        } else if (wid == 1) {
            // ---- primer: warm L2 two chunks ahead (no correctness dep) ----
            if (h + 2 < NH) {
                prime_chunk(gwin, (h + 2) * CHUNK, prow, pcol, dummy);
            }
            asm volatile("s_waitcnt vmcnt(0)" ::: "memory");
        } else {
            // ---- writers: flush out[h-1] (8 x 1KB each) ----
            if (h >= 1) {
                const int tbase = (h - 1) * CHUNK;
                const float4* o4 = (const float4*)&out_ring[(h - 1) & 1][0][0];
                #pragma unroll
                for (int k = 0; k < 8; ++k) {
                    const int f = (wid - 2) + 2 * k;   // 16 groups over 2 waves
                    const float4 vv = o4[f * 64 + lane];
                    const int    t  = tbase + 4 * f + prow;
                    *(float4*)(sbase + (size_t)t * LIF_D + pcol) = vv;
                }
                asm volatile("s_waitcnt lgkmcnt(0)" ::: "memory");
            }
        }
        __builtin_amdgcn_s_barrier();
        asm volatile("" ::: "memory");
    }

    // ---- epilogue: flush out[NH-1]; store final membrane ----
    if (wid >= 2) {
        const int tbase = (NH - 1) * CHUNK;
        const float4* o4 = (const float4*)&out_ring[(NH - 1) & 1][0][0];
        #pragma unroll
        for (int k = 0; k < 8; ++k) {
            const int f = (wid - 2) + 2 * k;
            const float4 vv = o4[f * 64 + lane];
            const int    t  = tbase + 4 * f + prow;
            *(float4*)(sbase + (size_t)t * LIF_D + pcol) = vv;
        }
    } else if (wid == 0) {
        mem_out[bb * LIF_D + ch0 + lane] = mem;
    }
}

extern "C" void kernel_launch(void* const* d_in, const int* in_sizes, int n_in,
                              void* d_out, int out_size, void* d_ws, size_t ws_size,
                              hipStream_t stream) {
    const float* current  = (const float*)d_in[0];   // [8, 4096, 1024]
    const float* membrane = (const float*)d_in[1];   // [8, 1024]

    float* spikes  = (float*)d_out;                                 // [8,4096,1024]
    float* mem_out = (float*)d_out + (size_t)LIF_B * LIF_S * LIF_D; // [8,1024]

    dim3 block(256);                   // w0 consumer, w1 primer, w2-3 writers
    dim3 grid(LIF_B * LIF_D / CPB);    // 128 blocks (64 channels each)

    hipLaunchKernelGGL(lif_v8_kernel, grid, block, 0, stream,
                       current, membrane, spikes, mem_out);
}

// Round 14
// 78.763 us; speedup vs baseline: 1.8002x; 1.6342x over previous
//
#include <hip/hip_runtime.h>

// LIF neuron forward, v9: bit-packed spikes — consumer has no per-step LDS writes.
// V = leak*V + I; spike = (V >= 1); V -= spike.
// current: [B=8, S=4096, D=1024] f32, membrane: [B, D] f32.
// Outputs concatenated: spikes [B,S,D] then mem_final [B,D], all f32.
//
// Evidence r5-r13: dur = 4096 x per-step latency of the serial chain;
// producers/writers/grid/barriers all invariant. ~55cy/step vs ~16cy chain:
// blamed on per-step ds_write + lgkm coupling with the read stream.
// v9 consumer: 16-deep batched ds_read input (waited once/batch), spike
// bits packed into 2 u32/lane per 64-step phase, ONE ds_write_b64/phase.
// Writers expand bits -> 1.0f/0.0f and store 1KB float4s (off-chain).
// Skeleton = v5 (best, 94.3us): 128 blocks, 4-slot in-ring, producer
// 3-ahead with vmcnt(32), raw s_barrier.
//
// Numerics (validated r5-r13, absmax 7.6e-6): forward spike == hard
// threshold exactly in fp32; fp contract(off) pins mul-then-add rounding;
// mem = f ? (v-1) : v bit-identical to v - spike.

#define LIF_B 8
#define LIF_S 4096
#define LIF_D 1024
#define CHUNK 64
#define NH    (LIF_S / CHUNK)   // 64
#define CPB   64                // channels per block

typedef __attribute__((address_space(3))) unsigned int lds_uint;
typedef const __attribute__((address_space(1))) unsigned int glb_uint;

__device__ __forceinline__ void stage_chunk(const float* gwin, int tb,
                                            int prow, int pcol,
                                            float* slotbase) {
    #pragma unroll
    for (int f = 0; f < CHUNK / 4; ++f) {
        const float* src = gwin + (size_t)(tb + 4 * f + prow) * LIF_D + pcol;
        __builtin_amdgcn_global_load_lds(
            (glb_uint*)(const void*)src,
            (lds_uint*)(void*)(slotbase + (size_t)4 * f * 64), 16, 0, 0);
    }
}

__global__ __launch_bounds__(256, 1) void lif_v9_kernel(
    const float* __restrict__ current,
    const float* __restrict__ membrane,
    float* __restrict__ spikes,
    float* __restrict__ mem_out)
{
    #pragma clang fp contract(off)

    __shared__ __align__(16) float in_ring[4][CHUNK][CPB];   // 64 KB
    __shared__ uint2 mask_lds[2][CPB];                       // 512 B spike bits

    const int wid  = threadIdx.x >> 6;   // 0=consumer 1=producer 2,3=writers
    const int lane = threadIdx.x & 63;
    const int blk  = blockIdx.x;         // 0..127
    const int bb   = blk >> 4;           // batch
    const int ch0  = (blk & 15) * CPB;

    const float* gwin  = current + (size_t)bb * LIF_S * LIF_D + ch0;
    float*       sbase = spikes  + (size_t)bb * LIF_S * LIF_D + ch0;

    const int prow = lane >> 4;          // 4-row group mapping
    const int pcol = (lane & 15) * 4;

    float mem = 0.0f;

    // ---- prologue: producer stages chunks 0..2; consumer loads membrane ----
    if (wid == 1) {
        stage_chunk(gwin, 0 * CHUNK, prow, pcol, &in_ring[0][0][0]);
        stage_chunk(gwin, 1 * CHUNK, prow, pcol, &in_ring[1][0][0]);
        stage_chunk(gwin, 2 * CHUNK, prow, pcol, &in_ring[2][0][0]);
        asm volatile("s_waitcnt vmcnt(32)" ::: "memory");  // chunk 0 landed
    } else if (wid == 0) {
        mem = membrane[bb * LIF_D + ch0 + lane];
    }
    __builtin_amdgcn_s_barrier();
    asm volatile("" ::: "memory");

    for (int h = 0; h < NH; ++h) {
        if (wid == 0) {
            // ---- consumer: 64 steps, bit-packed spikes, batched reads ----
            const float* ib = &in_ring[h & 3][0][lane];
            unsigned mask0 = 0u, mask1 = 0u;

            float A[16], Bb[16];
            #pragma unroll
            for (int j = 0; j < 16; ++j) A[j] = ib[j * CPB];         // rows 0-15
            #pragma unroll
            for (int j = 0; j < 16; ++j) Bb[j] = ib[(16 + j) * CPB]; // rows 16-31

            // batch 0: compute A (steps 0-15), prefetch rows 32-47 into A
            #pragma unroll
            for (int j = 0; j < 16; ++j) {
                const float v = 0.9f * mem + A[j];     // mul-then-add
                const float w = v - 1.0f;              // off chain
                const bool  f = (v >= 1.0f);
                mask0 |= f ? (1u << j) : 0u;           // off chain
                mem = f ? w : v;                       // soft reset
            }
            #pragma unroll
            for (int j = 0; j < 16; ++j) A[j] = ib[(32 + j) * CPB];

            // batch 1: compute Bb (steps 16-31), prefetch rows 48-63 into Bb
            #pragma unroll
            for (int j = 0; j < 16; ++j) {
                const float v = 0.9f * mem + Bb[j];
                const float w = v - 1.0f;
                const bool  f = (v >= 1.0f);
                mask0 |= f ? (1u << (16 + j)) : 0u;
                mem = f ? w : v;
            }
            #pragma unroll
            for (int j = 0; j < 16; ++j) Bb[j] = ib[(48 + j) * CPB];

            // batch 2: compute A (steps 32-47)
            #pragma unroll
            for (int j = 0; j < 16; ++j) {
                const float v = 0.9f * mem + A[j];
                const float w = v - 1.0f;
                const bool  f = (v >= 1.0f);
                mask1 |= f ? (1u << j) : 0u;
                mem = f ? w : v;
            }

            // batch 3: compute Bb (steps 48-63)
            #pragma unroll
            for (int j = 0; j < 16; ++j) {
                const float v = 0.9f * mem + Bb[j];
                const float w = v - 1.0f;
                const bool  f = (v >= 1.0f);
                mask1 |= f ? (1u << (16 + j)) : 0u;
                mem = f ? w : v;
            }

            mask_lds[h & 1][lane] = make_uint2(mask0, mask1);  // one ds_write_b64
            asm volatile("s_waitcnt lgkmcnt(0)" ::: "memory");
        } else if (wid == 1) {
            // ---- producer: stage chunk h+3; 32 loads stay in flight ----
            if (h + 3 < NH) {
                stage_chunk(gwin, (h + 3) * CHUNK, prow, pcol,
                            &in_ring[(h + 3) & 3][0][0]);
                asm volatile("s_waitcnt vmcnt(32)" ::: "memory");
            } else {
                asm volatile("s_waitcnt vmcnt(0)" ::: "memory");
            }
        } else {
            // ---- writers: expand + flush spike bits of phase h-1 ----
            if (h >= 1) {
                const int tbase = (h - 1) * CHUNK;
                uint2 mm[4];
                #pragma unroll
                for (int k = 0; k < 4; ++k)
                    mm[k] = mask_lds[(h - 1) & 1][pcol + k];
                #pragma unroll
                for (int k = 0; k < 8; ++k) {
                    const int f  = (wid - 2) + 2 * k;   // 16 groups over 2 waves
                    const int tl = 4 * f + prow;        // row in chunk, 0..63
                    const int b  = tl & 31;
                    float4 vv;
                    if (tl < 32) {
                        vv.x = ((mm[0].x >> b) & 1u) ? 1.0f : 0.0f;
                        vv.y = ((mm[1].x >> b) & 1u) ? 1.0f : 0.0f;
                        vv.z = ((mm[2].x >> b) & 1u) ? 1.0f : 0.0f;
                        vv.w = ((mm[3].x >> b) & 1u) ? 1.0f : 0.0f;
                    } else {
                        vv.x = ((mm[0].y >> b) & 1u) ? 1.0f : 0.0f;
                        vv.y = ((mm[1].y >> b) & 1u) ? 1.0f : 0.0f;
                        vv.z = ((mm[2].y >> b) & 1u) ? 1.0f : 0.0f;
                        vv.w = ((mm[3].y >> b) & 1u) ? 1.0f : 0.0f;
                    }
                    *(float4*)(sbase + (size_t)(tbase + tl) * LIF_D + pcol) = vv;
                }
                asm volatile("s_waitcnt lgkmcnt(0)" ::: "memory");
            }
        }
        __builtin_amdgcn_s_barrier();
        asm volatile("" ::: "memory");
    }

    // ---- epilogue: flush phase NH-1; store final membrane ----
    if (wid >= 2) {
        const int tbase = (NH - 1) * CHUNK;
        uint2 mm[4];
        #pragma unroll
        for (int k = 0; k < 4; ++k)
            mm[k] = mask_lds[(NH - 1) & 1][pcol + k];
        #pragma unroll
        for (int k = 0; k < 8; ++k) {
            const int f  = (wid - 2) + 2 * k;
            const int tl = 4 * f + prow;
            const int b  = tl & 31;
            float4 vv;
            if (tl < 32) {
                vv.x = ((mm[0].x >> b) & 1u) ? 1.0f : 0.0f;
                vv.y = ((mm[1].x >> b) & 1u) ? 1.0f : 0.0f;
                vv.z = ((mm[2].x >> b) & 1u) ? 1.0f : 0.0f;
                vv.w = ((mm[3].x >> b) & 1u) ? 1.0f : 0.0f;
            } else {
                vv.x = ((mm[0].y >> b) & 1u) ? 1.0f : 0.0f;
                vv.y = ((mm[1].y >> b) & 1u) ? 1.0f : 0.0f;
                vv.z = ((mm[2].y >> b) & 1u) ? 1.0f : 0.0f;
                vv.w = ((mm[3].y >> b) & 1u) ? 1.0f : 0.0f;
            }
            *(float4*)(sbase + (size_t)(tbase + tl) * LIF_D + pcol) = vv;
        }
    } else if (wid == 0) {
        mem_out[bb * LIF_D + ch0 + lane] = mem;
    }
}

extern "C" void kernel_launch(void* const* d_in, const int* in_sizes, int n_in,
                              void* d_out, int out_size, void* d_ws, size_t ws_size,
                              hipStream_t stream) {
    const float* current  = (const float*)d_in[0];   // [8, 4096, 1024]
    const float* membrane = (const float*)d_in[1];   // [8, 1024]

    float* spikes  = (float*)d_out;                                 // [8,4096,1024]
    float* mem_out = (float*)d_out + (size_t)LIF_B * LIF_S * LIF_D; // [8,1024]

    dim3 block(256);                   // w0 consumer, w1 producer, w2-3 writers
    dim3 grid(LIF_B * LIF_D / CPB);    // 128 blocks (64 channels each)

    hipLaunchKernelGGL(lif_v9_kernel, grid, block, 0, stream,
                       current, membrane, spikes, mem_out);
}

// Round 16
// 75.226 us; speedup vs baseline: 1.8849x; 1.0470x over previous
//
#include <hip/hip_runtime.h>

// LIF neuron forward, v10: v9 bit-packed consumer at CHUNK=256 (NH=16).
// V = leak*V + I; spike = (V >= 1); V -= spike.
// current: [B=8, S=4096, D=1024] f32, membrane: [B, D] f32.
// Outputs concatenated: spikes [B,S,D] then mem_final [B,D], all f32.
//
// v9 (78.8us, best): per-step 46cy; ~1400cy/phase overhead (barrier skew,
// mask drain, batch-0 LDS latency) paid 64x. v10 pays it 16x: CHUNK=256,
// 2-slot 128KB in-ring (v7 ring protocol), producer distance-1 vmcnt(0)
// (drain hides under ~12k-cy phase), consumer = 16 fully-static batches
// of 16 with 2-batch-ahead prefetch (v7's regression was runtime-indexed
// LDS from a non-unrolled loop; here every index is compile-time).
// Spikes packed 8 u32/lane; writers split by wid so mask-word selects
// stay static (wid2: rows 0-127/words 0-3, wid3: rows 128-255/words 4-7).
//
// Numerics (validated r5-r14, absmax 7.6e-6): forward spike == hard
// threshold exactly in fp32; fp contract(off) pins mul-then-add rounding;
// mem = f ? (v-1) : v bit-identical to v - spike.

#define LIF_B 8
#define LIF_S 4096
#define LIF_D 1024
#define CHUNK 256
#define NH    (LIF_S / CHUNK)   // 16
#define CPB   64                // channels per block

typedef __attribute__((address_space(3))) unsigned int lds_uint;
typedef const __attribute__((address_space(1))) unsigned int glb_uint;

// stage one 64KB chunk (256 rows x 64 ch) with 64 x 1KB global_load_lds.
__device__ __forceinline__ void stage_chunk(const float* gwin, int tb,
                                            int prow, int pcol,
                                            float* slotbase) {
    #pragma unroll
    for (int f = 0; f < CHUNK / 4; ++f) {
        const float* src = gwin + (size_t)(tb + 4 * f + prow) * LIF_D + pcol;
        __builtin_amdgcn_global_load_lds(
            (glb_uint*)(const void*)src,
            (lds_uint*)(void*)(slotbase + (size_t)4 * f * 64), 16, 0, 0);
    }
}

__global__ __launch_bounds__(256, 1) void lif_v10_kernel(
    const float* __restrict__ current,
    const float* __restrict__ membrane,
    float* __restrict__ spikes,
    float* __restrict__ mem_out)
{
    #pragma clang fp contract(off)

    __shared__ __align__(16) float in_ring[2][CHUNK][CPB];   // 128 KB
    __shared__ unsigned mask_lds[2][8][CPB];                 // 4 KB spike bits

    const int wid  = threadIdx.x >> 6;   // 0=consumer 1=producer 2,3=writers
    const int lane = threadIdx.x & 63;
    const int blk  = blockIdx.x;         // 0..127
    const int bb   = blk >> 4;           // batch
    const int ch0  = (blk & 15) * CPB;

    const float* gwin  = current + (size_t)bb * LIF_S * LIF_D + ch0;
    float*       sbase = spikes  + (size_t)bb * LIF_S * LIF_D + ch0;

    const int prow = lane >> 4;          // 4-row group mapping
    const int pcol = (lane & 15) * 4;

    float mem = 0.0f;

    // ---- prologue: producer stages chunk 0; consumer loads membrane ----
    if (wid == 1) {
        stage_chunk(gwin, 0, prow, pcol, &in_ring[0][0][0]);
        asm volatile("s_waitcnt vmcnt(0)" ::: "memory");
    } else if (wid == 0) {
        mem = membrane[bb * LIF_D + ch0 + lane];
    }
    __builtin_amdgcn_s_barrier();
    asm volatile("" ::: "memory");

    for (int h = 0; h < NH; ++h) {
        if (wid == 0) {
            // ---- consumer: 256 steps, 16 static batches of 16 ----
            const float* ib = &in_ring[h & 1][0][lane];
            unsigned m[8];
            #pragma unroll
            for (int j = 0; j < 8; ++j) m[j] = 0u;

            float A[16], Bv[16];
            #pragma unroll
            for (int j = 0; j < 16; ++j) A[j]  = ib[j * CPB];
            #pragma unroll
            for (int j = 0; j < 16; ++j) Bv[j] = ib[(16 + j) * CPB];

            #pragma unroll
            for (int b = 0; b < 16; ++b) {
                const int wd = b >> 1;          // mask word (static)
                const int sh = (b & 1) * 16;    // bit base (static)
                #pragma unroll
                for (int j = 0; j < 16; ++j) {
                    const float c = ((b & 1) == 0) ? A[j] : Bv[j];  // static
                    const float v = 0.9f * mem + c;   // mul-then-add
                    const float w = v - 1.0f;         // off chain
                    const bool  f = (v >= 1.0f);
                    m[wd] |= f ? (1u << (sh + j)) : 0u;
                    mem = f ? w : v;                  // soft reset
                }
                if (b + 2 < 16) {                     // prefetch batch b+2
                    #pragma unroll
                    for (int j = 0; j < 16; ++j) {
                        if ((b & 1) == 0) A[j]  = ib[((b + 2) * 16 + j) * CPB];
                        else              Bv[j] = ib[((b + 2) * 16 + j) * CPB];
                    }
                }
            }

            #pragma unroll
            for (int j = 0; j < 8; ++j)
                mask_lds[h & 1][j][lane] = m[j];      // 8x ds_write_b32
            asm volatile("s_waitcnt lgkmcnt(0)" ::: "memory");
        } else if (wid == 1) {
            // ---- producer: stage chunk h+1 into the other slot ----
            if (h + 1 < NH) {
                stage_chunk(gwin, (h + 1) * CHUNK, prow, pcol,
                            &in_ring[(h + 1) & 1][0][0]);
                asm volatile("s_waitcnt vmcnt(0)" ::: "memory");
            }
        } else {
            // ---- writers: expand + flush spike bits of phase h-1 ----
            if (h >= 1) {
                const int tb = (h - 1) * CHUNK;
                const unsigned* mw = &mask_lds[(h - 1) & 1][0][0];
                const int wbase = (wid == 3) ? 4 : 0;     // word half
                const int rbase = (wid == 3) ? 128 : 0;   // row half
                unsigned M[4][4];                          // [ch][word] static
                #pragma unroll
                for (int c = 0; c < 4; ++c)
                    #pragma unroll
                    for (int w = 0; w < 4; ++w)
                        M[c][w] = mw[(wbase + w) * CPB + pcol + c];
                #pragma unroll
                for (int k = 0; k < 32; ++k) {
                    const int widx = k >> 3;               // static 0..3
                    const unsigned bit = (unsigned)(((4 * k) & 31) + prow);
                    float4 vv;
                    vv.x = ((M[0][widx] >> bit) & 1u) ? 1.0f : 0.0f;
                    vv.y = ((M[1][widx] >> bit) & 1u) ? 1.0f : 0.0f;
                    vv.z = ((M[2][widx] >> bit) & 1u) ? 1.0f : 0.0f;
                    vv.w = ((M[3][widx] >> bit) & 1u) ? 1.0f : 0.0f;
                    const int tl = rbase + 4 * k + prow;
                    *(float4*)(sbase + (size_t)(tb + tl) * LIF_D + pcol) = vv;
                }
                asm volatile("s_waitcnt lgkmcnt(0)" ::: "memory");
            }
        }
        __builtin_amdgcn_s_barrier();
        asm volatile("" ::: "memory");
    }

    // ---- epilogue: flush phase NH-1; store final membrane ----
    if (wid >= 2) {
        const int tb = (NH - 1) * CHUNK;
        const unsigned* mw = &mask_lds[(NH - 1) & 1][0][0];
        const int wbase = (wid == 3) ? 4 : 0;
        const int rbase = (wid == 3) ? 128 : 0;
        unsigned M[4][4];
        #pragma unroll
        for (int c = 0; c < 4; ++c)
            #pragma unroll
            for (int w = 0; w < 4; ++w)
                M[c][w] = mw[(wbase + w) * CPB + pcol + c];
        #pragma unroll
        for (int k = 0; k < 32; ++k) {
            const int widx = k >> 3;
            const unsigned bit = (unsigned)(((4 * k) & 31) + prow);
            float4 vv;
            vv.x = ((M[0][widx] >> bit) & 1u) ? 1.0f : 0.0f;
            vv.y = ((M[1][widx] >> bit) & 1u) ? 1.0f : 0.0f;
            vv.z = ((M[2][widx] >> bit) & 1u) ? 1.0f : 0.0f;
            vv.w = ((M[3][widx] >> bit) & 1u) ? 1.0f : 0.0f;
            const int tl = rbase + 4 * k + prow;
            *(float4*)(sbase + (size_t)(tb + tl) * LIF_D + pcol) = vv;
        }
    } else if (wid == 0) {
        mem_out[bb * LIF_D + ch0 + lane] = mem;
    }
}

extern "C" void kernel_launch(void* const* d_in, const int* in_sizes, int n_in,
                              void* d_out, int out_size, void* d_ws, size_t ws_size,
                              hipStream_t stream) {
    const float* current  = (const float*)d_in[0];   // [8, 4096, 1024]
    const float* membrane = (const float*)d_in[1];   // [8, 1024]

    float* spikes  = (float*)d_out;                                 // [8,4096,1024]
    float* mem_out = (float*)d_out + (size_t)LIF_B * LIF_S * LIF_D; // [8,1024]

    dim3 block(256);                   // w0 consumer, w1 producer, w2-3 writers
    dim3 grid(LIF_B * LIF_D / CPB);    // 128 blocks (64 channels each)

    hipLaunchKernelGGL(lif_v10_kernel, grid, block, 0, stream,
                       current, membrane, spikes, mem_out);
}

// Round 17
// 73.638 us; speedup vs baseline: 1.9255x; 1.0216x over previous
//
#include <hip/hip_runtime.h>

// LIF neuron forward, v11: hand-scheduled asm chain + wave-mask-in-SGPR.
// V = leak*V + I; spike = (V >= 1); V -= spike.
// current: [B=8, S=4096, D=1024] f32, membrane: [B, D] f32.
// Outputs concatenated: spikes [B,S,D] then mem_final [B,D], all f32.
//
// Evidence r5-r16: dur = 4096 x consumer cadence (~44cy/step at v9/v10),
// invariant to producer/writer/grid/phase-count. Chain floor = mul->add->
// cmp->cndmask ~16cy. v11 cuts cadence: per-step inline asm {v_mul 0.9,
// v_add c, v_add -1 (off-chain w), v_cmp_ge -> SGPR PAIR (wave spike mask
// for free), v_cndmask mem} + one v_writelane to bank the mask word.
// Spike->float expansion moves entirely to writer waves. CPB=32/256 blocks
// so all CUs stream (BW for the faster cadence). v10 skeleton otherwise:
// CHUNK=256, NH=16, raw s_barrier, producer distance-1 vmcnt(0).
//
// Numerics: asm chain is the identical op sequence/order validated r5-r16
// (absmax 7.6e-6): mul-then-add (0x3f666666 = 0.9f), cmp>=1.0,
// mem = f ? v-1 : v. Bit-exact vs numpy fp32 replay.

#define LIF_B 8
#define LIF_S 4096
#define LIF_D 1024
#define CHUNK 256
#define NH    (LIF_S / CHUNK)   // 16
#define CPB   32                // channels per block

typedef __attribute__((address_space(3))) unsigned int lds_uint;
typedef const __attribute__((address_space(1))) unsigned int glb_uint;

// stage one 32KB chunk (256 rows x 32 ch) with 32 x 1KB global_load_lds.
// lane L -> row (L>>3), float col (L&7)*4; LDS dest linear (m173 pattern).
__device__ __forceinline__ void stage_chunk32(const float* gwin, int tb,
                                              int prow, int pcol,
                                              float* slotbase) {
    #pragma unroll
    for (int f = 0; f < CHUNK / 8; ++f) {
        const float* src = gwin + (size_t)(tb + 8 * f + prow) * LIF_D + pcol;
        __builtin_amdgcn_global_load_lds(
            (glb_uint*)(const void*)src,
            (lds_uint*)(void*)(slotbase + (size_t)f * 256), 16, 0, 0);
    }
}

// One LIF step: chain in asm; wave spike-mask lands in an SGPR pair; its
// low word (lanes 0-31 = this block's 32 channels) is banked into lane LB
// of vml via v_writelane (immediate lane select).
template<int LB>
__device__ __forceinline__ void lif_step(float c, float& mem, unsigned& vml) {
    float v_, w_;
    unsigned long long mk_;
    asm volatile(
        "v_mul_f32 %1, 0x3f666666, %3\n\t"   // v = 0.9f * mem (mul first)
        "v_add_f32 %1, %1, %4\n\t"           // v += c
        "v_add_f32 %2, -1.0, %1\n\t"         // w = v - 1  (off critical path)
        "v_cmp_ge_f32 %0, %1, 1.0\n\t"       // wave mask -> SGPR pair
        "v_cndmask_b32 %3, %1, %2, %0"       // mem = f ? w : v
        : "=&s"(mk_), "=&v"(v_), "=&v"(w_), "+v"(mem)
        : "v"(c));
    asm volatile("v_writelane_b32 %0, %1, %2"
                 : "+v"(vml)
                 : "s"((unsigned)mk_), "n"(LB));
}

#define LIF_B16_A()  do { \
    lif_step< 0>(A[ 0], mem, vml); lif_step< 1>(A[ 1], mem, vml); \
    lif_step< 2>(A[ 2], mem, vml); lif_step< 3>(A[ 3], mem, vml); \
    lif_step< 4>(A[ 4], mem, vml); lif_step< 5>(A[ 5], mem, vml); \
    lif_step< 6>(A[ 6], mem, vml); lif_step< 7>(A[ 7], mem, vml); \
    lif_step< 8>(A[ 8], mem, vml); lif_step< 9>(A[ 9], mem, vml); \
    lif_step<10>(A[10], mem, vml); lif_step<11>(A[11], mem, vml); \
    lif_step<12>(A[12], mem, vml); lif_step<13>(A[13], mem, vml); \
    lif_step<14>(A[14], mem, vml); lif_step<15>(A[15], mem, vml); } while (0)

#define LIF_B16_B()  do { \
    lif_step<16>(Bv[ 0], mem, vml); lif_step<17>(Bv[ 1], mem, vml); \
    lif_step<18>(Bv[ 2], mem, vml); lif_step<19>(Bv[ 3], mem, vml); \
    lif_step<20>(Bv[ 4], mem, vml); lif_step<21>(Bv[ 5], mem, vml); \
    lif_step<22>(Bv[ 6], mem, vml); lif_step<23>(Bv[ 7], mem, vml); \
    lif_step<24>(Bv[ 8], mem, vml); lif_step<25>(Bv[ 9], mem, vml); \
    lif_step<26>(Bv[10], mem, vml); lif_step<27>(Bv[11], mem, vml); \
    lif_step<28>(Bv[12], mem, vml); lif_step<29>(Bv[13], mem, vml); \
    lif_step<30>(Bv[14], mem, vml); lif_step<31>(Bv[15], mem, vml); } while (0)

__global__ __launch_bounds__(256, 1) void lif_v11_kernel(
    const float* __restrict__ current,
    const float* __restrict__ membrane,
    float* __restrict__ spikes,
    float* __restrict__ mem_out)
{
    #pragma clang fp contract(off)

    __shared__ __align__(16) float in_ring[2][CHUNK][CPB];   // 64 KB
    __shared__ unsigned mask_lds[2][8][64];                  // 4 KB step masks

    const int wid  = threadIdx.x >> 6;   // 0=consumer 1=producer 2,3=writers
    const int lane = threadIdx.x & 63;
    const int blk  = blockIdx.x;         // 0..255
    const int bb   = blk >> 5;           // batch (1024/32 = 32 ch-blocks)
    const int ch0  = (blk & 31) * CPB;

    const float* gwin  = current + (size_t)bb * LIF_S * LIF_D + ch0;
    float*       sbase = spikes  + (size_t)bb * LIF_S * LIF_D + ch0;

    const int prow = lane >> 3;          // producer 8-row mapping
    const int pcol = (lane & 7) * 4;

    float mem = 0.0f;

    // ---- prologue: producer stages chunk 0; consumer loads membrane ----
    if (wid == 1) {
        stage_chunk32(gwin, 0, prow, pcol, &in_ring[0][0][0]);
        asm volatile("s_waitcnt vmcnt(0)" ::: "memory");
    } else if (wid == 0 && lane < CPB) {
        mem = membrane[bb * LIF_D + ch0 + lane];
    }
    __builtin_amdgcn_s_barrier();
    asm volatile("" ::: "memory");

    for (int h = 0; h < NH; ++h) {
        if (wid == 0) {
            // ---- consumer: 256 steps = 8 groups of 32, asm chain ----
            const float* ib = &in_ring[h & 1][0][lane & 31];
            float A[16], Bv[16];
            #pragma unroll
            for (int j = 0; j < 16; ++j) A[j]  = ib[j * CPB];
            #pragma unroll
            for (int j = 0; j < 16; ++j) Bv[j] = ib[(16 + j) * CPB];
            unsigned vml = 0;

            #pragma unroll
            for (int g = 0; g < 8; ++g) {
                LIF_B16_A();
                if (g < 7) {
                    #pragma unroll
                    for (int j = 0; j < 16; ++j)
                        A[j] = ib[((2 * g + 2) * 16 + j) * CPB];
                }
                LIF_B16_B();
                mask_lds[h & 1][g][lane] = vml;   // step-masks of group g
                if (g < 7) {
                    #pragma unroll
                    for (int j = 0; j < 16; ++j)
                        Bv[j] = ib[((2 * g + 3) * 16 + j) * CPB];
                }
            }
            asm volatile("s_waitcnt lgkmcnt(0)" ::: "memory");
        } else if (wid == 1) {
            // ---- producer: stage chunk h+1 into the other slot ----
            if (h + 1 < NH) {
                stage_chunk32(gwin, (h + 1) * CHUNK, prow, pcol,
                              &in_ring[(h + 1) & 1][0][0]);
                asm volatile("s_waitcnt vmcnt(0)" ::: "memory");
            }
        } else {
            // ---- writers: expand step-masks of phase h-1 -> floats ----
            if (h >= 1) {
                const int ph = (h - 1) & 1;
                const int tb = (h - 1) * CHUNK;
                const int rbase = (wid == 3) ? 128 : 0;
                const int sub = lane >> 5;      // 0/1: which of 2 rows
                const int chb = lane & 31;      // channel = bit index
                #pragma unroll 8
                for (int k = 0; k < 64; ++k) {
                    const int rt = rbase + 2 * k + sub;             // row
                    const unsigned m = mask_lds[ph][rt >> 5][rt & 31];
                    const float sv = (float)((m >> chb) & 1u);      // 0/1
                    sbase[(size_t)(tb + rt) * LIF_D + chb] = sv;
                }
                asm volatile("s_waitcnt lgkmcnt(0)" ::: "memory");
            }
        }
        __builtin_amdgcn_s_barrier();
        asm volatile("" ::: "memory");
    }

    // ---- epilogue: flush masks of phase NH-1; store final membrane ----
    if (wid >= 2) {
        const int ph = (NH - 1) & 1;
        const int tb = (NH - 1) * CHUNK;
        const int rbase = (wid == 3) ? 128 : 0;
        const int sub = lane >> 5;
        const int chb = lane & 31;
        #pragma unroll 8
        for (int k = 0; k < 64; ++k) {
            const int rt = rbase + 2 * k + sub;
            const unsigned m = mask_lds[ph][rt >> 5][rt & 31];
            const float sv = (float)((m >> chb) & 1u);
            sbase[(size_t)(tb + rt) * LIF_D + chb] = sv;
        }
    } else if (wid == 0 && lane < CPB) {
        mem_out[bb * LIF_D + ch0 + lane] = mem;
    }
}

extern "C" void kernel_launch(void* const* d_in, const int* in_sizes, int n_in,
                              void* d_out, int out_size, void* d_ws, size_t ws_size,
                              hipStream_t stream) {
    const float* current  = (const float*)d_in[0];   // [8, 4096, 1024]
    const float* membrane = (const float*)d_in[1];   // [8, 1024]

    float* spikes  = (float*)d_out;                                 // [8,4096,1024]
    float* mem_out = (float*)d_out + (size_t)LIF_B * LIF_S * LIF_D; // [8,1024]

    dim3 block(256);                   // w0 consumer, w1 producer, w2-3 writers
    dim3 grid(LIF_B * LIF_D / CPB);    // 256 blocks (32 channels each)

    hipLaunchKernelGGL(lif_v11_kernel, grid, block, 0, stream,
                       current, membrane, spikes, mem_out);
}